// Round 10
// baseline (251.385 us; speedup 1.0000x reference)
//
#include <hip/hip_runtime.h>
#include <hip/hip_bf16.h>
#include <math.h>

// Shapes (fixed by the reference)
#define Bdim 16
#define Ndim 1024
#define Ddim 256
#define Hdim 8
#define HDdim 32
#define INdim 256
#define HIDdim 1024
#define Tdim (Bdim * Ndim)   // 16384 rows

typedef __attribute__((ext_vector_type(8)))  short bf16x8;
typedef __attribute__((ext_vector_type(4)))  short bf16x4;
typedef __attribute__((ext_vector_type(16))) float f32x16;
typedef unsigned int u32;

__device__ inline short f2bf(float x) {
    union { __hip_bfloat16 b; short s; } u;
    u.b = __float2bfloat16(x);
    return u.s;
}

// pack two f32 -> two bf16 (round-to-nearest via +0x8000; inputs never NaN)
__device__ inline u32 pack2bf(float a, float b) {
    u32 ua = __float_as_uint(a), ub = __float_as_uint(b);
    return ((ua + 0x8000u) >> 16) | ((ub + 0x8000u) & 0xffff0000u);
}

__device__ inline float gelu_exact(float v) {
    return 0.5f * v * (1.0f + erff(v * 0.70710678118654752f));
}

// ---------------------------------------------------------------------------
// fp32 -> bf16 converter (weights)
// ---------------------------------------------------------------------------
__global__ __launch_bounds__(256) void cvt_kernel(const float* __restrict__ src,
                                                  short* __restrict__ dst, int n4) {
    int i = blockIdx.x * 256 + threadIdx.x;
    if (i < n4) {
        float4 v = ((const float4*)src)[i];
        bf16x4 b;
        b[0] = f2bf(v.x); b[1] = f2bf(v.y); b[2] = f2bf(v.z); b[3] = f2bf(v.w);
        ((bf16x4*)dst)[i] = b;
    }
}

// ---------------------------------------------------------------------------
// LayerNorm, wave-per-row (4 rows/block), float4 vectorized.
// ---------------------------------------------------------------------------
__global__ __launch_bounds__(256) void ln4_kernel(const float* __restrict__ x,
                                                  const float* __restrict__ g,
                                                  const float* __restrict__ b,
                                                  float* __restrict__ outf,
                                                  short* __restrict__ outb) {
    int w = threadIdx.x >> 6, lane = threadIdx.x & 63;
    int row = blockIdx.x * 4 + w;
    float4 v = ((const float4*)x)[(size_t)row * 64 + lane];
    float s  = (v.x + v.y) + (v.z + v.w);
    float s2 = (v.x * v.x + v.y * v.y) + (v.z * v.z + v.w * v.w);
    #pragma unroll
    for (int off = 32; off; off >>= 1) {
        s  += __shfl_xor(s,  off, 64);
        s2 += __shfl_xor(s2, off, 64);
    }
    float mu   = s * (1.0f / Ddim);
    float var  = s2 * (1.0f / Ddim) - mu * mu;
    float rstd = rsqrtf(var + 1e-5f);
    float4 gg = ((const float4*)g)[lane];
    float4 bb = ((const float4*)b)[lane];
    float4 r;
    r.x = (v.x - mu) * rstd * gg.x + bb.x;
    r.y = (v.y - mu) * rstd * gg.y + bb.y;
    r.z = (v.z - mu) * rstd * gg.z + bb.z;
    r.w = (v.w - mu) * rstd * gg.w + bb.w;
    if (outf) ((float4*)outf)[(size_t)row * 64 + lane] = r;
    bf16x4 rb;
    rb[0] = f2bf(r.x); rb[1] = f2bf(r.y); rb[2] = f2bf(r.z); rb[3] = f2bf(r.w);
    ((bf16x4*)outb)[(size_t)row * 64 + lane] = rb;
}

// ---------------------------------------------------------------------------
// MFMA GEMM with register-prefetch double-buffering (R9-passing core).
// EPI_QKV additionally folds attn scale*log2e into the q columns (cn<256).
// ---------------------------------------------------------------------------
#define EPI_NONE 0
#define EPI_PROJ 1
#define EPI_GELU 2
#define EPI_RES  3
#define EPI_QKV  4

#define GPAD 40
#define SCALE2Q 0.25505654249892417f   // 32^-0.5 * log2(e)

template <int EPI, int BN>
__global__ __launch_bounds__(256) void gemm_mfma(const short* __restrict__ A,
                                                 const short* __restrict__ W,
                                                 void* __restrict__ Cv,
                                                 int M, int N, int K,
                                                 const float* __restrict__ bias,
                                                 const float* __restrict__ add1,
                                                 const float* __restrict__ add2) {
    __shared__ short As[128 * GPAD];
    __shared__ short Bs[BN * GPAD];
    const int tid = threadIdx.x, w = tid >> 6, lane = tid & 63;
    const int col = lane & 31;
    const int half_id = lane >> 5;
    const int m0 = blockIdx.y * 128, n0 = blockIdx.x * BN;
    const int wm = (BN == 128) ? (w & 1) * 64 : w * 32;
    const int wn = (BN == 128) ? (w >> 1) * 64 : 0;
    constexpr int TM = (BN == 128) ? 2 : 1;

    f32x16 acc[TM][2];
    #pragma unroll
    for (int i = 0; i < TM; ++i) { acc[i][0] = 0.0f; acc[i][1] = 0.0f; }

    const int sra = tid >> 1, ssa = (tid & 1) * 2;
    const int srb = (BN == 128) ? (tid >> 1) : (tid >> 2);
    const int ssb = (BN == 128) ? (tid & 1) * 2 : (tid & 3);

    const short* pAsrc = &A[(size_t)(m0 + sra) * K + ssa * 8];
    const short* pBsrc = &W[(size_t)(n0 + srb) * K + ssb * 8];

    bf16x8 pa0, pa1, pb0, pb1;
    pa0 = *(const bf16x8*)&pAsrc[0];
    pa1 = *(const bf16x8*)&pAsrc[8];
    pb0 = *(const bf16x8*)&pBsrc[0];
    if (BN == 128) pb1 = *(const bf16x8*)&pBsrc[8];

    const int T = K >> 5;
    for (int kt = 0; kt < T; ++kt) {
        __syncthreads();
        *(bf16x8*)&As[sra * GPAD + ssa * 8]     = pa0;
        *(bf16x8*)&As[sra * GPAD + ssa * 8 + 8] = pa1;
        *(bf16x8*)&Bs[srb * GPAD + ssb * 8]     = pb0;
        if (BN == 128) *(bf16x8*)&Bs[srb * GPAD + ssb * 8 + 8] = pb1;
        __syncthreads();

        if (kt + 1 < T) {
            const short* a = pAsrc + (kt + 1) * 32;
            const short* b = pBsrc + (kt + 1) * 32;
            pa0 = *(const bf16x8*)&a[0];
            pa1 = *(const bf16x8*)&a[8];
            pb0 = *(const bf16x8*)&b[0];
            if (BN == 128) pb1 = *(const bf16x8*)&b[8];
        }

        #pragma unroll
        for (int ks = 0; ks < 2; ++ks) {
            bf16x8 af[TM], bfv[2];
            #pragma unroll
            for (int t = 0; t < TM; ++t)
                af[t] = *(const bf16x8*)&As[(wm + t * 32 + col) * GPAD + ks * 16 + half_id * 8];
            #pragma unroll
            for (int t = 0; t < 2; ++t)
                bfv[t] = *(const bf16x8*)&Bs[(wn + t * 32 + col) * GPAD + ks * 16 + half_id * 8];
            #pragma unroll
            for (int tm = 0; tm < TM; ++tm)
                #pragma unroll
                for (int tn = 0; tn < 2; ++tn)
                    acc[tm][tn] = __builtin_amdgcn_mfma_f32_32x32x16_bf16(
                        af[tm], bfv[tn], acc[tm][tn], 0, 0, 0);
        }
    }

    float* Cf = (float*)Cv;
    short* Cb = (short*)Cv;
    #pragma unroll
    for (int tm = 0; tm < TM; ++tm) {
        #pragma unroll
        for (int r = 0; r < 16; ++r) {
            int row = m0 + wm + tm * 32 + (r & 3) + 8 * (r >> 2) + 4 * half_id;
            #pragma unroll
            for (int tn = 0; tn < 2; ++tn) {
                int cn = n0 + wn + tn * 32 + col;
                size_t off = (size_t)row * N + cn;
                float v = acc[tm][tn][r];
                if (EPI != EPI_NONE && EPI != EPI_QKV) v += bias[cn];
                if (EPI == EPI_QKV && cn < 256) v *= SCALE2Q;
                if (EPI == EPI_GELU) v = gelu_exact(v);
                if (EPI == EPI_PROJ) v += add1[off] + add2[off];
                if (EPI == EPI_RES)  v += add1[off];
                if (EPI == EPI_PROJ || EPI == EPI_RES) Cf[off] = v;
                else                                   Cb[off] = f2bf(v);
            }
        }
    }
}

// ---------------------------------------------------------------------------
// One-time V transpose: qkv[b][n][512+head*32+d] -> vT[(bh*32+d)][n].
// ---------------------------------------------------------------------------
#define VTPAD 136

__global__ __launch_bounds__(256) void vtrans_kernel(const short* __restrict__ qkv,
                                                     short* __restrict__ vT) {
    __shared__ short Tl[32 * VTPAD];
    const int tid = threadIdx.x;
    const int bh = blockIdx.x, c = blockIdx.y;
    const int b = bh >> 3, head = bh & 7;
    {
        int r = tid >> 1, hv = tid & 1;
        const short* src = qkv + (size_t)b * Ndim * 768 + (size_t)(c * 128 + r) * 768
                           + 512 + head * 32 + hv * 16;
        bf16x8 v0 = *(const bf16x8*)&src[0];
        bf16x8 v1 = *(const bf16x8*)&src[8];
        #pragma unroll
        for (int i = 0; i < 8; ++i) {
            Tl[(hv * 16 + i) * VTPAD + r]     = v0[i];
            Tl[(hv * 16 + 8 + i) * VTPAD + r] = v1[i];
        }
    }
    __syncthreads();
    {
        int d = tid >> 3, j16 = (tid & 7) * 16;
        short* dst = vT + (size_t)(bh * 32 + d) * Ndim + c * 128 + j16;
        *(bf16x8*)&dst[0] = *(const bf16x8*)&Tl[d * VTPAD + j16];
        *(bf16x8*)&dst[8] = *(const bf16x8*)&Tl[d * VTPAD + j16 + 8];
    }
}

// ---------------------------------------------------------------------------
// MFMA attention, j-split flash (maxless => partials additive).
// Grid (qblock, bh, part): each block does 128q x 512j, writes unnormalized
// O partial (fp32) + l partial. Q pre-scaled by scale*log2e in qkv GEMM.
// l computed by MFMA vs ones-frag -> same C-layout rows as o_acc (no shuffles).
// Ps double-buffered on jt parity to overlap PV(jt) with S(jt+1).
// ---------------------------------------------------------------------------
#define KVPAD 40
#define CHUNK 128

__global__ __launch_bounds__(256) void attn_mfma_kernel(const short* __restrict__ qkv,
                                                        const short* __restrict__ vT,
                                                        float* __restrict__ opart,
                                                        float* __restrict__ lpart) {
    __shared__ short Ks[CHUNK * KVPAD];
    __shared__ short Vt[32 * VTPAD];
    __shared__ short Ps[4][2][32 * KVPAD];

    const int tid = threadIdx.x;
    const int w = tid >> 6;
    const int lane = tid & 63;
    const int col = lane & 31;
    const int half_id = lane >> 5;

    const int bh = blockIdx.y;
    const int b = bh >> 3, head = bh & 7;
    const int q0w = blockIdx.x * 128 + w * 32;
    const int part = blockIdx.z;

    const size_t qkvb = (size_t)b * Ndim * 768;
    float* op = opart + (size_t)part * Tdim * 256;
    float* lp = lpart + (size_t)part * Tdim * 8;

    bf16x8 qf[2];
    {
        const short* qrow = qkv + qkvb + (size_t)(q0w + col) * 768 + head * 32;
        #pragma unroll
        for (int kh = 0; kh < 2; ++kh)
            qf[kh] = *(const bf16x8*)&qrow[kh * 16 + half_id * 8];
    }

    bf16x8 vone;
    #pragma unroll
    for (int i = 0; i < 8; ++i) vone[i] = (short)0x3F80;   // bf16 1.0

    f32x16 o_acc = 0.0f, l_acc = 0.0f;

    const int c0 = part * 4;
    for (int c = c0; c < c0 + 4; ++c) {
        if (c != c0) __syncthreads();
        {
            int r = tid >> 1, hv = tid & 1;
            const short* src = qkv + qkvb + (size_t)(c * CHUNK + r) * 768
                               + head * 32 + hv * 16;
            *(bf16x8*)&Ks[r * KVPAD + hv * 16]     = *(const bf16x8*)&src[256];
            *(bf16x8*)&Ks[r * KVPAD + hv * 16 + 8] = *(const bf16x8*)&src[256 + 8];
            int d = tid >> 3, j16 = (tid & 7) * 16;
            const short* vsrc = vT + (size_t)(bh * 32 + d) * Ndim + c * CHUNK + j16;
            *(bf16x8*)&Vt[d * VTPAD + j16]     = *(const bf16x8*)&vsrc[0];
            *(bf16x8*)&Vt[d * VTPAD + j16 + 8] = *(const bf16x8*)&vsrc[8];
        }
        __syncthreads();

        #pragma unroll
        for (int jt = 0; jt < 4; ++jt) {
            short* ps = &Ps[w][jt & 1][0];
            bf16x8 kf0 = *(bf16x8*)&Ks[(jt * 32 + col) * KVPAD + half_id * 8];
            bf16x8 kf1 = *(bf16x8*)&Ks[(jt * 32 + col) * KVPAD + 16 + half_id * 8];
            bf16x8 vf0 = *(bf16x8*)&Vt[col * VTPAD + jt * 32 + half_id * 8];
            bf16x8 vf1 = *(bf16x8*)&Vt[col * VTPAD + jt * 32 + 16 + half_id * 8];

            f32x16 s_acc = 0.0f;
            s_acc = __builtin_amdgcn_mfma_f32_32x32x16_bf16(kf0, qf[0], s_acc, 0, 0, 0);
            s_acc = __builtin_amdgcn_mfma_f32_32x32x16_bf16(kf1, qf[1], s_acc, 0, 0, 0);

            #pragma unroll
            for (int g = 0; g < 4; ++g) {
                float e0 = exp2f(s_acc[g * 4 + 0]);
                float e1 = exp2f(s_acc[g * 4 + 1]);
                float e2 = exp2f(s_acc[g * 4 + 2]);
                float e3 = exp2f(s_acc[g * 4 + 3]);
                uint2 pk;
                pk.x = pack2bf(e0, e1);
                pk.y = pack2bf(e2, e3);
                *(uint2*)&ps[col * KVPAD + g * 8 + half_id * 4] = pk;
            }

            bf16x8 pf0 = *(bf16x8*)&ps[col * KVPAD + half_id * 8];
            bf16x8 pf1 = *(bf16x8*)&ps[col * KVPAD + 16 + half_id * 8];
            o_acc = __builtin_amdgcn_mfma_f32_32x32x16_bf16(pf0, vf0, o_acc, 0, 0, 0);
            o_acc = __builtin_amdgcn_mfma_f32_32x32x16_bf16(pf1, vf1, o_acc, 0, 0, 0);
            l_acc = __builtin_amdgcn_mfma_f32_32x32x16_bf16(pf0, vone, l_acc, 0, 0, 0);
            l_acc = __builtin_amdgcn_mfma_f32_32x32x16_bf16(pf1, vone, l_acc, 0, 0, 0);
        }
    }

    // epilogue: unnormalized O partial + l partial (no shuffles needed)
    #pragma unroll
    for (int r = 0; r < 16; ++r) {
        int q_r = (r & 3) + 8 * (r >> 2) + 4 * half_id;
        size_t gq = (size_t)(b * Ndim + q0w + q_r);
        op[gq * INdim + head * 32 + col] = o_acc[r];
    }
    if (col < 16) {
        int r = col;
        int q_r = (r & 3) + 8 * (r >> 2) + 4 * half_id;
        lp[(size_t)(b * Ndim + q0w + q_r) * 8 + head] = l_acc[r];
    }
}

// ---------------------------------------------------------------------------
// Combine j-partitions: oat = (O0+O1) / (l0+l1), bf16 out.
// ---------------------------------------------------------------------------
__global__ __launch_bounds__(256) void combine_kernel(const float* __restrict__ opart,
                                                      const float* __restrict__ lpart,
                                                      short* __restrict__ oat) {
    int i = blockIdx.x * 256 + threadIdx.x;       // one float4 per thread
    size_t i4 = (size_t)i * 4;
    int gq = (int)(i4 >> 8);
    int head = ((int)(i4 & 255)) >> 5;
    float4 a = ((const float4*)opart)[i];
    float4 b = ((const float4*)(opart + (size_t)Tdim * 256))[i];
    float l = lpart[(size_t)gq * 8 + head] + lpart[(size_t)Tdim * 8 + (size_t)gq * 8 + head];
    float rl = 1.0f / l;
    bf16x4 rb;
    rb[0] = f2bf((a.x + b.x) * rl);
    rb[1] = f2bf((a.y + b.y) * rl);
    rb[2] = f2bf((a.z + b.z) * rl);
    rb[3] = f2bf((a.w + b.w) * rl);
    ((bf16x4*)oat)[i] = rb;
}

// ---------------------------------------------------------------------------
// launch
// ---------------------------------------------------------------------------
extern "C" void kernel_launch(void* const* d_in, const int* in_sizes, int n_in,
                              void* d_out, int out_size, void* d_ws, size_t ws_size,
                              hipStream_t stream) {
    const float* x     = (const float*)d_in[0];
    const float* g1    = (const float*)d_in[2];
    const float* b1    = (const float*)d_in[3];
    const float* Wqkv  = (const float*)d_in[4];
    const float* Wproj = (const float*)d_in[5];
    const float* bproj = (const float*)d_in[6];
    const float* g2    = (const float*)d_in[7];
    const float* b2    = (const float*)d_in[8];
    const float* W1    = (const float*)d_in[9];
    const float* bb1   = (const float*)d_in[10];
    const float* W2    = (const float*)d_in[11];
    const float* bb2   = (const float*)d_in[12];
    float* out = (float*)d_out;

    // workspace (<= 96 MiB, proven by R1):
    //  [0,16M)  h fp32
    //  [16,24M) h_bf (LN1; reused by LN2)
    //  [24,48M) qkv_bf (dead after attn)  -> xnew fp32 [24,40M), oat_bf [40,48M)
    //  [48,64M) opart0 fp32 (dead after combine) -> mid_bf [48,80M)
    //  [64,80M) opart1 fp32
    //  [80,81M) lpart fp32 [2][Tdim*8]
    //  [81,89M) vT bf16
    //  [89,91M) weights bf16
    char* ws = (char*)d_ws;
    float* h      = (float*)(ws);
    short* h_bf   = (short*)(ws + (size_t)(16u << 20));
    short* qkv_bf = (short*)(ws + (size_t)(24u << 20));
    float* xnew   = (float*)(ws + (size_t)(24u << 20));
    short* oat_bf = (short*)(ws + (size_t)(40u << 20));
    float* opart  = (float*)(ws + (size_t)(48u << 20));
    short* mid_bf = (short*)(ws + (size_t)(48u << 20));
    float* lpart  = (float*)(ws + (size_t)(80u << 20));
    short* vT     = (short*)(ws + (size_t)(81u << 20));
    short* wqkv_b = (short*)(ws + (size_t)(89u << 20));
    short* wproj_b= (short*)(ws + (size_t)(89u << 20) + 768 * 1024);
    short* w1_b   = (short*)(ws + (size_t)(90u << 20));
    short* w2_b   = (short*)(ws + (size_t)(90u << 20) + 512 * 1024);

    // 0) weights -> bf16
    cvt_kernel<<<(3 * INdim * Ddim / 4 + 255) / 256, 256, 0, stream>>>(Wqkv, wqkv_b, 3 * INdim * Ddim / 4);
    cvt_kernel<<<(INdim * INdim / 4 + 255) / 256, 256, 0, stream>>>(Wproj, wproj_b, INdim * INdim / 4);
    cvt_kernel<<<(HIDdim * Ddim / 4 + 255) / 256, 256, 0, stream>>>(W1, w1_b, HIDdim * Ddim / 4);
    cvt_kernel<<<(Ddim * HIDdim / 4 + 255) / 256, 256, 0, stream>>>(W2, w2_b, Ddim * HIDdim / 4);

    // 1) LN1: x -> h (fp32) + h_bf
    ln4_kernel<<<Tdim / 4, 256, 0, stream>>>(x, g1, b1, h, h_bf);
    // 2) qkv_bf = h_bf @ Wqkv^T, q columns pre-scaled by 32^-0.5*log2e
    gemm_mfma<EPI_QKV, 128><<<dim3(768 / 128, Tdim / 128), 256, 0, stream>>>(
        h_bf, wqkv_b, qkv_bf, Tdim, 768, 256, nullptr, nullptr, nullptr);
    // 2b) V transpose (once)
    vtrans_kernel<<<dim3(Bdim * Hdim, Ndim / 128), 256, 0, stream>>>(qkv_bf, vT);
    // 3) attention partials (j-split x2)
    attn_mfma_kernel<<<dim3(Ndim / 128, Bdim * Hdim, 2), 256, 0, stream>>>(
        qkv_bf, vT, opart, lpart);
    // 3b) combine -> oat_bf
    combine_kernel<<<(Tdim * INdim / 4) / 256, 256, 0, stream>>>(opart, lpart, oat_bf);
    // 4) xnew = oat @ Wproj^T + bproj + h + x
    gemm_mfma<EPI_PROJ, 64><<<dim3(256 / 64, Tdim / 128), 256, 0, stream>>>(
        oat_bf, wproj_b, xnew, Tdim, 256, 256, bproj, h, x);
    // 5) LN2: xnew -> h_bf
    ln4_kernel<<<Tdim / 4, 256, 0, stream>>>(xnew, g2, b2, nullptr, h_bf);
    // 6) mid_bf = gelu(h2 @ W1^T + bb1)
    gemm_mfma<EPI_GELU, 128><<<dim3(1024 / 128, Tdim / 128), 256, 0, stream>>>(
        h_bf, w1_b, mid_bf, Tdim, 1024, 256, bb1, nullptr, nullptr);
    // 7) out = xnew + mid @ W2^T + bb2
    gemm_mfma<EPI_RES, 64><<<dim3(256 / 64, Tdim / 128), 256, 0, stream>>>(
        mid_bf, w2_b, out, Tdim, 256, 1024, bb2, xnew, nullptr);
}

// Round 11
// 237.674 us; speedup vs baseline: 1.0577x; 1.0577x over previous
//
#include <hip/hip_runtime.h>
#include <hip/hip_bf16.h>
#include <math.h>

// Shapes (fixed by the reference)
#define Bdim 16
#define Ndim 1024
#define Ddim 256
#define Hdim 8
#define HDdim 32
#define INdim 256
#define HIDdim 1024
#define Tdim (Bdim * Ndim)   // 16384 rows

typedef __attribute__((ext_vector_type(8)))  short bf16x8;
typedef __attribute__((ext_vector_type(4)))  short bf16x4;
typedef __attribute__((ext_vector_type(16))) float f32x16;
typedef unsigned int u32;

__device__ inline short f2bf(float x) {
    union { __hip_bfloat16 b; short s; } u;
    u.b = __float2bfloat16(x);
    return u.s;
}

__device__ inline float bf2f(short s) {
    return __uint_as_float(((u32)(unsigned short)s) << 16);
}

// pack two f32 -> two bf16 in a u32
__device__ inline u32 pack2bf(float a, float b) {
#if __has_builtin(__builtin_amdgcn_cvt_pk_bf16_f32)
    typedef __attribute__((ext_vector_type(2))) __bf16 bf16x2_t;
    union { bf16x2_t v; u32 u; } c;
    c.v = __builtin_amdgcn_cvt_pk_bf16_f32(a, b);
    return c.u;
#else
    u32 ua = __float_as_uint(a), ub = __float_as_uint(b);
    return ((ua + 0x8000u) >> 16) | ((ub + 0x8000u) & 0xffff0000u);
#endif
}

__device__ inline float gelu_exact(float v) {
    return 0.5f * v * (1.0f + erff(v * 0.70710678118654752f));
}

// ---------------------------------------------------------------------------
// All four weight matrices -> bf16 in ONE dispatch (segment by flat index)
// ---------------------------------------------------------------------------
#define N4_QKV  (3 * INdim * Ddim / 4)   // 49152
#define N4_PROJ (INdim * INdim / 4)      // 16384
#define N4_W1   (HIDdim * Ddim / 4)      // 65536
#define N4_W2   (Ddim * HIDdim / 4)      // 65536

__global__ __launch_bounds__(256) void cvt_all_kernel(const float* __restrict__ s0,
                                                      const float* __restrict__ s1,
                                                      const float* __restrict__ s2,
                                                      const float* __restrict__ s3,
                                                      short* __restrict__ d0,
                                                      short* __restrict__ d1,
                                                      short* __restrict__ d2,
                                                      short* __restrict__ d3) {
    int i = blockIdx.x * 256 + threadIdx.x;
    const float* src; short* dst; int j;
    if (i < N4_QKV)                          { src = s0; dst = d0; j = i; }
    else if (i < N4_QKV + N4_PROJ)           { src = s1; dst = d1; j = i - N4_QKV; }
    else if (i < N4_QKV + N4_PROJ + N4_W1)   { src = s2; dst = d2; j = i - N4_QKV - N4_PROJ; }
    else                                     { src = s3; dst = d3; j = i - N4_QKV - N4_PROJ - N4_W1; }
    float4 v = ((const float4*)src)[j];
    bf16x4 b;
    b[0] = f2bf(v.x); b[1] = f2bf(v.y); b[2] = f2bf(v.z); b[3] = f2bf(v.w);
    ((bf16x4*)dst)[j] = b;
}

// ---------------------------------------------------------------------------
// LayerNorm, wave-per-row (4 rows/block), float4 vectorized.
// ---------------------------------------------------------------------------
__global__ __launch_bounds__(256) void ln4_kernel(const float* __restrict__ x,
                                                  const float* __restrict__ g,
                                                  const float* __restrict__ b,
                                                  float* __restrict__ outf,
                                                  short* __restrict__ outb) {
    int w = threadIdx.x >> 6, lane = threadIdx.x & 63;
    int row = blockIdx.x * 4 + w;
    float4 v = ((const float4*)x)[(size_t)row * 64 + lane];
    float s  = (v.x + v.y) + (v.z + v.w);
    float s2 = (v.x * v.x + v.y * v.y) + (v.z * v.z + v.w * v.w);
    #pragma unroll
    for (int off = 32; off; off >>= 1) {
        s  += __shfl_xor(s,  off, 64);
        s2 += __shfl_xor(s2, off, 64);
    }
    float mu   = s * (1.0f / Ddim);
    float var  = s2 * (1.0f / Ddim) - mu * mu;
    float rstd = rsqrtf(var + 1e-5f);
    float4 gg = ((const float4*)g)[lane];
    float4 bb = ((const float4*)b)[lane];
    float4 r;
    r.x = (v.x - mu) * rstd * gg.x + bb.x;
    r.y = (v.y - mu) * rstd * gg.y + bb.y;
    r.z = (v.z - mu) * rstd * gg.z + bb.z;
    r.w = (v.w - mu) * rstd * gg.w + bb.w;
    if (outf) ((float4*)outf)[(size_t)row * 64 + lane] = r;
    bf16x4 rb;
    rb[0] = f2bf(r.x); rb[1] = f2bf(r.y); rb[2] = f2bf(r.z); rb[3] = f2bf(r.w);
    ((bf16x4*)outb)[(size_t)row * 64 + lane] = rb;
}

// ---------------------------------------------------------------------------
// MFMA GEMM, BK=64 (halved barrier count vs R10), register-prefetch dbuf.
// C[M,N] = A[M,K] @ W[N,K]^T (+epi). 128(M) x BN tile.
// BN=128: 4 waves x 2x2 of 32x32. BN=64: 4 waves x 1x2.
// ---------------------------------------------------------------------------
#define EPI_NONE 0
#define EPI_PROJ 1
#define EPI_GELU 2
#define EPI_RES  3
#define EPI_QKV  4

#define GPAD64 72   // shorts per LDS row (64 data + 8 pad)
#define SCALE2Q 0.25505654249892417f   // 32^-0.5 * log2(e)

template <int EPI, int BN>
__global__ __launch_bounds__(256) void gemm_mfma(const short* __restrict__ A,
                                                 const short* __restrict__ W,
                                                 void* __restrict__ Cv,
                                                 int M, int N, int K,
                                                 const float* __restrict__ bias,
                                                 const float* __restrict__ add1,
                                                 const float* __restrict__ add2) {
    __shared__ short As[128 * GPAD64];   // 18.4 KB
    __shared__ short Bs[BN * GPAD64];
    const int tid = threadIdx.x, w = tid >> 6, lane = tid & 63;
    const int col = lane & 31;
    const int half_id = lane >> 5;
    const int m0 = blockIdx.y * 128, n0 = blockIdx.x * BN;
    const int wm = (BN == 128) ? (w & 1) * 64 : w * 32;
    const int wn = (BN == 128) ? (w >> 1) * 64 : 0;
    constexpr int TM = (BN == 128) ? 2 : 1;

    f32x16 acc[TM][2];
    #pragma unroll
    for (int i = 0; i < TM; ++i) { acc[i][0] = 0.0f; acc[i][1] = 0.0f; }

    // staging maps (BK=64)
    const int sra = tid >> 1, ssa = (tid & 1) * 32;          // A: 4 regs/thread
    const int srb = (BN == 128) ? (tid >> 1) : (tid >> 2);
    const int ssb = (BN == 128) ? (tid & 1) * 32 : (tid & 3) * 16;
    constexpr int NB = (BN == 128) ? 4 : 2;                  // B regs/thread

    const short* pAsrc = &A[(size_t)(m0 + sra) * K + ssa];
    const short* pBsrc = &W[(size_t)(n0 + srb) * K + ssb];

    bf16x8 pa[4], pb[NB];
    #pragma unroll
    for (int j = 0; j < 4; ++j) pa[j] = *(const bf16x8*)&pAsrc[j * 8];
    #pragma unroll
    for (int j = 0; j < NB; ++j) pb[j] = *(const bf16x8*)&pBsrc[j * 8];

    const int T = K >> 6;
    for (int kt = 0; kt < T; ++kt) {
        __syncthreads();
        #pragma unroll
        for (int j = 0; j < 4; ++j) *(bf16x8*)&As[sra * GPAD64 + ssa + j * 8] = pa[j];
        #pragma unroll
        for (int j = 0; j < NB; ++j) *(bf16x8*)&Bs[srb * GPAD64 + ssb + j * 8] = pb[j];
        __syncthreads();

        if (kt + 1 < T) {
            const short* a = pAsrc + (kt + 1) * 64;
            const short* b = pBsrc + (kt + 1) * 64;
            #pragma unroll
            for (int j = 0; j < 4; ++j) pa[j] = *(const bf16x8*)&a[j * 8];
            #pragma unroll
            for (int j = 0; j < NB; ++j) pb[j] = *(const bf16x8*)&b[j * 8];
        }

        #pragma unroll
        for (int ks = 0; ks < 4; ++ks) {
            bf16x8 af[TM], bfv[2];
            #pragma unroll
            for (int t = 0; t < TM; ++t)
                af[t] = *(const bf16x8*)&As[(wm + t * 32 + col) * GPAD64 + ks * 16 + half_id * 8];
            #pragma unroll
            for (int t = 0; t < 2; ++t)
                bfv[t] = *(const bf16x8*)&Bs[(wn + t * 32 + col) * GPAD64 + ks * 16 + half_id * 8];
            #pragma unroll
            for (int tm = 0; tm < TM; ++tm)
                #pragma unroll
                for (int tn = 0; tn < 2; ++tn)
                    acc[tm][tn] = __builtin_amdgcn_mfma_f32_32x32x16_bf16(
                        af[tm], bfv[tn], acc[tm][tn], 0, 0, 0);
        }
    }

    // epilogue: C/D layout col=lane&31, row=(reg&3)+8*(reg>>2)+4*(lane>>5)
    float* Cf = (float*)Cv;
    short* Cb = (short*)Cv;
    #pragma unroll
    for (int tm = 0; tm < TM; ++tm) {
        #pragma unroll
        for (int r = 0; r < 16; ++r) {
            int row = m0 + wm + tm * 32 + (r & 3) + 8 * (r >> 2) + 4 * half_id;
            #pragma unroll
            for (int tn = 0; tn < 2; ++tn) {
                int cn = n0 + wn + tn * 32 + col;
                size_t off = (size_t)row * N + cn;
                float v = acc[tm][tn][r];
                if (EPI != EPI_NONE && EPI != EPI_QKV) v += bias[cn];
                if (EPI == EPI_QKV && cn < 256) v *= SCALE2Q;
                if (EPI == EPI_GELU) v = gelu_exact(v);
                if (EPI == EPI_PROJ) v += add1[off] + add2[off];
                if (EPI == EPI_RES)  v += add1[off];
                if (EPI == EPI_PROJ || EPI == EPI_RES) Cf[off] = v;
                else                                   Cb[off] = f2bf(v);
            }
        }
    }
}

// ---------------------------------------------------------------------------
// One-time V transpose: qkv[b][n][512+head*32+d] -> vT[(bh*32+d)][n].
// ---------------------------------------------------------------------------
#define VTPAD 136

__global__ __launch_bounds__(256) void vtrans_kernel(const short* __restrict__ qkv,
                                                     short* __restrict__ vT) {
    __shared__ short Tl[32 * VTPAD];
    const int tid = threadIdx.x;
    const int bh = blockIdx.x, c = blockIdx.y;
    const int b = bh >> 3, head = bh & 7;
    {
        int r = tid >> 1, hv = tid & 1;
        const short* src = qkv + (size_t)b * Ndim * 768 + (size_t)(c * 128 + r) * 768
                           + 512 + head * 32 + hv * 16;
        bf16x8 v0 = *(const bf16x8*)&src[0];
        bf16x8 v1 = *(const bf16x8*)&src[8];
        #pragma unroll
        for (int i = 0; i < 8; ++i) {
            Tl[(hv * 16 + i) * VTPAD + r]     = v0[i];
            Tl[(hv * 16 + 8 + i) * VTPAD + r] = v1[i];
        }
    }
    __syncthreads();
    {
        int d = tid >> 3, j16 = (tid & 7) * 16;
        short* dst = vT + (size_t)(bh * 32 + d) * Ndim + c * 128 + j16;
        *(bf16x8*)&dst[0] = *(const bf16x8*)&Tl[d * VTPAD + j16];
        *(bf16x8*)&dst[8] = *(const bf16x8*)&Tl[d * VTPAD + j16 + 8];
    }
}

// ---------------------------------------------------------------------------
// MFMA attention, j-split flash (maxless -> partials additive). Partials bf16.
// ---------------------------------------------------------------------------
#define KVPAD 40
#define CHUNK 128

__global__ __launch_bounds__(256) void attn_mfma_kernel(const short* __restrict__ qkv,
                                                        const short* __restrict__ vT,
                                                        short* __restrict__ opart,
                                                        float* __restrict__ lpart) {
    __shared__ short Ks[CHUNK * KVPAD];
    __shared__ short Vt[32 * VTPAD];
    __shared__ short Ps[4][2][32 * KVPAD];

    const int tid = threadIdx.x;
    const int w = tid >> 6;
    const int lane = tid & 63;
    const int col = lane & 31;
    const int half_id = lane >> 5;

    const int bh = blockIdx.y;
    const int b = bh >> 3, head = bh & 7;
    const int q0w = blockIdx.x * 128 + w * 32;
    const int part = blockIdx.z;

    const size_t qkvb = (size_t)b * Ndim * 768;
    short* op = opart + (size_t)part * Tdim * 256;
    float* lp = lpart + (size_t)part * Tdim * 8;

    bf16x8 qf[2];
    {
        const short* qrow = qkv + qkvb + (size_t)(q0w + col) * 768 + head * 32;
        #pragma unroll
        for (int kh = 0; kh < 2; ++kh)
            qf[kh] = *(const bf16x8*)&qrow[kh * 16 + half_id * 8];
    }

    bf16x8 vone;
    #pragma unroll
    for (int i = 0; i < 8; ++i) vone[i] = (short)0x3F80;   // bf16 1.0

    f32x16 o_acc = 0.0f, l_acc = 0.0f;

    const int c0 = part * 4;
    for (int c = c0; c < c0 + 4; ++c) {
        if (c != c0) __syncthreads();
        {
            int r = tid >> 1, hv = tid & 1;
            const short* src = qkv + qkvb + (size_t)(c * CHUNK + r) * 768
                               + head * 32 + hv * 16;
            *(bf16x8*)&Ks[r * KVPAD + hv * 16]     = *(const bf16x8*)&src[256];
            *(bf16x8*)&Ks[r * KVPAD + hv * 16 + 8] = *(const bf16x8*)&src[256 + 8];
            int d = tid >> 3, j16 = (tid & 7) * 16;
            const short* vsrc = vT + (size_t)(bh * 32 + d) * Ndim + c * CHUNK + j16;
            *(bf16x8*)&Vt[d * VTPAD + j16]     = *(const bf16x8*)&vsrc[0];
            *(bf16x8*)&Vt[d * VTPAD + j16 + 8] = *(const bf16x8*)&vsrc[8];
        }
        __syncthreads();

        #pragma unroll
        for (int jt = 0; jt < 4; ++jt) {
            short* ps = &Ps[w][jt & 1][0];
            bf16x8 kf0 = *(bf16x8*)&Ks[(jt * 32 + col) * KVPAD + half_id * 8];
            bf16x8 kf1 = *(bf16x8*)&Ks[(jt * 32 + col) * KVPAD + 16 + half_id * 8];
            bf16x8 vf0 = *(bf16x8*)&Vt[col * VTPAD + jt * 32 + half_id * 8];
            bf16x8 vf1 = *(bf16x8*)&Vt[col * VTPAD + jt * 32 + 16 + half_id * 8];

            f32x16 s_acc = 0.0f;
            s_acc = __builtin_amdgcn_mfma_f32_32x32x16_bf16(kf0, qf[0], s_acc, 0, 0, 0);
            s_acc = __builtin_amdgcn_mfma_f32_32x32x16_bf16(kf1, qf[1], s_acc, 0, 0, 0);

            #pragma unroll
            for (int g = 0; g < 4; ++g) {
                float e0 = exp2f(s_acc[g * 4 + 0]);
                float e1 = exp2f(s_acc[g * 4 + 1]);
                float e2 = exp2f(s_acc[g * 4 + 2]);
                float e3 = exp2f(s_acc[g * 4 + 3]);
                uint2 pk;
                pk.x = pack2bf(e0, e1);
                pk.y = pack2bf(e2, e3);
                *(uint2*)&ps[col * KVPAD + g * 8 + half_id * 4] = pk;
            }

            bf16x8 pf0 = *(bf16x8*)&ps[col * KVPAD + half_id * 8];
            bf16x8 pf1 = *(bf16x8*)&ps[col * KVPAD + 16 + half_id * 8];
            o_acc = __builtin_amdgcn_mfma_f32_32x32x16_bf16(pf0, vf0, o_acc, 0, 0, 0);
            o_acc = __builtin_amdgcn_mfma_f32_32x32x16_bf16(pf1, vf1, o_acc, 0, 0, 0);
            l_acc = __builtin_amdgcn_mfma_f32_32x32x16_bf16(pf0, vone, l_acc, 0, 0, 0);
            l_acc = __builtin_amdgcn_mfma_f32_32x32x16_bf16(pf1, vone, l_acc, 0, 0, 0);
        }
    }

    // epilogue: unnormalized O partial (bf16) + l partial (fp32)
    #pragma unroll
    for (int r = 0; r < 16; ++r) {
        int q_r = (r & 3) + 8 * (r >> 2) + 4 * half_id;
        size_t gq = (size_t)(b * Ndim + q0w + q_r);
        op[gq * INdim + head * 32 + col] = f2bf(o_acc[r]);
    }
    if (col < 16) {
        int r = col;
        int q_r = (r & 3) + 8 * (r >> 2) + 4 * half_id;
        lp[(size_t)(b * Ndim + q0w + q_r) * 8 + head] = l_acc[r];
    }
}

// ---------------------------------------------------------------------------
// Combine j-partitions: oat = (O0+O1) / (l0+l1), bf16 in/out, 8 elems/thread.
// ---------------------------------------------------------------------------
__global__ __launch_bounds__(256) void combine_kernel(const short* __restrict__ opart,
                                                      const float* __restrict__ lpart,
                                                      short* __restrict__ oat) {
    int i = blockIdx.x * 256 + threadIdx.x;       // one bf16x8 per thread
    size_t base = (size_t)i * 8;
    int gq = (int)(base >> 8);
    int head = ((int)(base & 255)) >> 5;
    bf16x8 a = ((const bf16x8*)opart)[i];
    bf16x8 b = ((const bf16x8*)(opart + (size_t)Tdim * 256))[i];
    float l = lpart[(size_t)gq * 8 + head] + lpart[(size_t)Tdim * 8 + (size_t)gq * 8 + head];
    float rl = 1.0f / l;
    bf16x8 r;
    #pragma unroll
    for (int j = 0; j < 8; ++j) r[j] = f2bf((bf2f(a[j]) + bf2f(b[j])) * rl);
    ((bf16x8*)oat)[i] = r;
}

// ---------------------------------------------------------------------------
// launch
// ---------------------------------------------------------------------------
extern "C" void kernel_launch(void* const* d_in, const int* in_sizes, int n_in,
                              void* d_out, int out_size, void* d_ws, size_t ws_size,
                              hipStream_t stream) {
    const float* x     = (const float*)d_in[0];
    const float* g1    = (const float*)d_in[2];
    const float* b1    = (const float*)d_in[3];
    const float* Wqkv  = (const float*)d_in[4];
    const float* Wproj = (const float*)d_in[5];
    const float* bproj = (const float*)d_in[6];
    const float* g2    = (const float*)d_in[7];
    const float* b2    = (const float*)d_in[8];
    const float* W1    = (const float*)d_in[9];
    const float* bb1   = (const float*)d_in[10];
    const float* W2    = (const float*)d_in[11];
    const float* bb2   = (const float*)d_in[12];
    float* out = (float*)d_out;

    // workspace:
    //  [0,16M)  h fp32
    //  [16,24M) h_bf
    //  [24,48M) qkv_bf (dead after attn) -> xnew fp32 [24,40M), oat_bf [40,48M)
    //  [48,64M) opart bf16 x2 (dead after combine) -> mid_bf [48,80M)
    //  [80,81M) lpart fp32 [2][Tdim*8]
    //  [81,89M) vT bf16
    //  [89,91M) weights bf16
    char* ws = (char*)d_ws;
    float* h      = (float*)(ws);
    short* h_bf   = (short*)(ws + (size_t)(16u << 20));
    short* qkv_bf = (short*)(ws + (size_t)(24u << 20));
    float* xnew   = (float*)(ws + (size_t)(24u << 20));
    short* oat_bf = (short*)(ws + (size_t)(40u << 20));
    short* opart  = (short*)(ws + (size_t)(48u << 20));
    short* mid_bf = (short*)(ws + (size_t)(48u << 20));
    float* lpart  = (float*)(ws + (size_t)(80u << 20));
    short* vT     = (short*)(ws + (size_t)(81u << 20));
    short* wqkv_b = (short*)(ws + (size_t)(89u << 20));
    short* wproj_b= (short*)(ws + (size_t)(89u << 20) + 768 * 1024);
    short* w1_b   = (short*)(ws + (size_t)(90u << 20));
    short* w2_b   = (short*)(ws + (size_t)(90u << 20) + 512 * 1024);

    // 0) all weights -> bf16 (single dispatch)
    cvt_all_kernel<<<(N4_QKV + N4_PROJ + N4_W1 + N4_W2 + 255) / 256, 256, 0, stream>>>(
        Wqkv, Wproj, W1, W2, wqkv_b, wproj_b, w1_b, w2_b);

    // 1) LN1: x -> h (fp32) + h_bf
    ln4_kernel<<<Tdim / 4, 256, 0, stream>>>(x, g1, b1, h, h_bf);
    // 2) qkv_bf = h_bf @ Wqkv^T, q columns pre-scaled by 32^-0.5*log2e
    gemm_mfma<EPI_QKV, 128><<<dim3(768 / 128, Tdim / 128), 256, 0, stream>>>(
        h_bf, wqkv_b, qkv_bf, Tdim, 768, 256, nullptr, nullptr, nullptr);
    // 2b) V transpose (once)
    vtrans_kernel<<<dim3(Bdim * Hdim, Ndim / 128), 256, 0, stream>>>(qkv_bf, vT);
    // 3) attention partials (j-split x2)
    attn_mfma_kernel<<<dim3(Ndim / 128, Bdim * Hdim, 2), 256, 0, stream>>>(
        qkv_bf, vT, opart, lpart);
    // 3b) combine -> oat_bf
    combine_kernel<<<(Tdim * INdim / 8) / 256, 256, 0, stream>>>(opart, lpart, oat_bf);
    // 4) xnew = oat @ Wproj^T + bproj + h + x
    gemm_mfma<EPI_PROJ, 64><<<dim3(256 / 64, Tdim / 128), 256, 0, stream>>>(
        oat_bf, wproj_b, xnew, Tdim, 256, 256, bproj, h, x);
    // 5) LN2: xnew -> h_bf
    ln4_kernel<<<Tdim / 4, 256, 0, stream>>>(xnew, g2, b2, nullptr, h_bf);
    // 6) mid_bf = gelu(h2 @ W1^T + bb1)
    gemm_mfma<EPI_GELU, 128><<<dim3(1024 / 128, Tdim / 128), 256, 0, stream>>>(
        h_bf, w1_b, mid_bf, Tdim, 1024, 256, bb1, nullptr, nullptr);
    // 7) out = xnew + mid @ W2^T + bb2
    gemm_mfma<EPI_RES, 64><<<dim3(256 / 64, Tdim / 128), 256, 0, stream>>>(
        mid_bf, w2_b, out, Tdim, 256, 1024, bb2, xnew, nullptr);
}

// Round 12
// 222.568 us; speedup vs baseline: 1.1295x; 1.0679x over previous
//
#include <hip/hip_runtime.h>
#include <hip/hip_bf16.h>
#include <math.h>

// Shapes (fixed by the reference)
#define Bdim 16
#define Ndim 1024
#define Ddim 256
#define Hdim 8
#define HDdim 32
#define INdim 256
#define HIDdim 1024
#define Tdim (Bdim * Ndim)   // 16384 rows

typedef __attribute__((ext_vector_type(8)))  short bf16x8;
typedef __attribute__((ext_vector_type(4)))  short bf16x4;
typedef __attribute__((ext_vector_type(16))) float f32x16;
typedef unsigned int u32;

__device__ inline short f2bf(float x) {
    union { __hip_bfloat16 b; short s; } u;
    u.b = __float2bfloat16(x);
    return u.s;
}

__device__ inline float bf2f(short s) {
    return __uint_as_float(((u32)(unsigned short)s) << 16);
}

// raw v_exp_f32 (scores are bounded; no libm range handling needed)
__device__ inline float fexp2(float x) {
#if __has_builtin(__builtin_amdgcn_exp2f)
    return __builtin_amdgcn_exp2f(x);
#else
    return exp2f(x);
#endif
}

// pack two f32 -> two bf16 in a u32
__device__ inline u32 pack2bf(float a, float b) {
#if __has_builtin(__builtin_amdgcn_cvt_pk_bf16_f32)
    typedef __attribute__((ext_vector_type(2))) __bf16 bf16x2_t;
    union { bf16x2_t v; u32 u; } c;
    c.v = __builtin_amdgcn_cvt_pk_bf16_f32(a, b);
    return c.u;
#else
    u32 ua = __float_as_uint(a), ub = __float_as_uint(b);
    return ((ua + 0x8000u) >> 16) | ((ub + 0x8000u) & 0xffff0000u);
#endif
}

__device__ inline float gelu_exact(float v) {
    return 0.5f * v * (1.0f + erff(v * 0.70710678118654752f));
}

// ---------------------------------------------------------------------------
// All four weight matrices -> bf16 in ONE dispatch (segment by flat index)
// ---------------------------------------------------------------------------
#define N4_QKV  (3 * INdim * Ddim / 4)   // 49152
#define N4_PROJ (INdim * INdim / 4)      // 16384
#define N4_W1   (HIDdim * Ddim / 4)      // 65536
#define N4_W2   (Ddim * HIDdim / 4)      // 65536

__global__ __launch_bounds__(256) void cvt_all_kernel(const float* __restrict__ s0,
                                                      const float* __restrict__ s1,
                                                      const float* __restrict__ s2,
                                                      const float* __restrict__ s3,
                                                      short* __restrict__ d0,
                                                      short* __restrict__ d1,
                                                      short* __restrict__ d2,
                                                      short* __restrict__ d3) {
    int i = blockIdx.x * 256 + threadIdx.x;
    const float* src; short* dst; int j;
    if (i < N4_QKV)                          { src = s0; dst = d0; j = i; }
    else if (i < N4_QKV + N4_PROJ)           { src = s1; dst = d1; j = i - N4_QKV; }
    else if (i < N4_QKV + N4_PROJ + N4_W1)   { src = s2; dst = d2; j = i - N4_QKV - N4_PROJ; }
    else                                     { src = s3; dst = d3; j = i - N4_QKV - N4_PROJ - N4_W1; }
    float4 v = ((const float4*)src)[j];
    bf16x4 b;
    b[0] = f2bf(v.x); b[1] = f2bf(v.y); b[2] = f2bf(v.z); b[3] = f2bf(v.w);
    ((bf16x4*)dst)[j] = b;
}

// ---------------------------------------------------------------------------
// LayerNorm, wave-per-row (4 rows/block), float4 vectorized.
// ---------------------------------------------------------------------------
__global__ __launch_bounds__(256) void ln4_kernel(const float* __restrict__ x,
                                                  const float* __restrict__ g,
                                                  const float* __restrict__ b,
                                                  float* __restrict__ outf,
                                                  short* __restrict__ outb) {
    int w = threadIdx.x >> 6, lane = threadIdx.x & 63;
    int row = blockIdx.x * 4 + w;
    float4 v = ((const float4*)x)[(size_t)row * 64 + lane];
    float s  = (v.x + v.y) + (v.z + v.w);
    float s2 = (v.x * v.x + v.y * v.y) + (v.z * v.z + v.w * v.w);
    #pragma unroll
    for (int off = 32; off; off >>= 1) {
        s  += __shfl_xor(s,  off, 64);
        s2 += __shfl_xor(s2, off, 64);
    }
    float mu   = s * (1.0f / Ddim);
    float var  = s2 * (1.0f / Ddim) - mu * mu;
    float rstd = rsqrtf(var + 1e-5f);
    float4 gg = ((const float4*)g)[lane];
    float4 bb = ((const float4*)b)[lane];
    float4 r;
    r.x = (v.x - mu) * rstd * gg.x + bb.x;
    r.y = (v.y - mu) * rstd * gg.y + bb.y;
    r.z = (v.z - mu) * rstd * gg.z + bb.z;
    r.w = (v.w - mu) * rstd * gg.w + bb.w;
    if (outf) ((float4*)outf)[(size_t)row * 64 + lane] = r;
    bf16x4 rb;
    rb[0] = f2bf(r.x); rb[1] = f2bf(r.y); rb[2] = f2bf(r.z); rb[3] = f2bf(r.w);
    ((bf16x4*)outb)[(size_t)row * 64 + lane] = rb;
}

// ---------------------------------------------------------------------------
// MFMA GEMM, BK=64, register-prefetch dbuf (R11-passing core).
// ---------------------------------------------------------------------------
#define EPI_NONE 0
#define EPI_PROJ 1
#define EPI_GELU 2
#define EPI_RES  3
#define EPI_QKV  4

#define GPAD64 72   // shorts per LDS row (64 data + 8 pad)
#define SCALE2Q 0.25505654249892417f   // 32^-0.5 * log2(e)

template <int EPI, int BN>
__global__ __launch_bounds__(256) void gemm_mfma(const short* __restrict__ A,
                                                 const short* __restrict__ W,
                                                 void* __restrict__ Cv,
                                                 int M, int N, int K,
                                                 const float* __restrict__ bias,
                                                 const float* __restrict__ add1,
                                                 const float* __restrict__ add2) {
    __shared__ short As[128 * GPAD64];
    __shared__ short Bs[BN * GPAD64];
    const int tid = threadIdx.x, w = tid >> 6, lane = tid & 63;
    const int col = lane & 31;
    const int half_id = lane >> 5;
    const int m0 = blockIdx.y * 128, n0 = blockIdx.x * BN;
    const int wm = (BN == 128) ? (w & 1) * 64 : w * 32;
    const int wn = (BN == 128) ? (w >> 1) * 64 : 0;
    constexpr int TM = (BN == 128) ? 2 : 1;

    f32x16 acc[TM][2];
    #pragma unroll
    for (int i = 0; i < TM; ++i) { acc[i][0] = 0.0f; acc[i][1] = 0.0f; }

    const int sra = tid >> 1, ssa = (tid & 1) * 32;
    const int srb = (BN == 128) ? (tid >> 1) : (tid >> 2);
    const int ssb = (BN == 128) ? (tid & 1) * 32 : (tid & 3) * 16;
    constexpr int NB = (BN == 128) ? 4 : 2;

    const short* pAsrc = &A[(size_t)(m0 + sra) * K + ssa];
    const short* pBsrc = &W[(size_t)(n0 + srb) * K + ssb];

    bf16x8 pa[4], pb[NB];
    #pragma unroll
    for (int j = 0; j < 4; ++j) pa[j] = *(const bf16x8*)&pAsrc[j * 8];
    #pragma unroll
    for (int j = 0; j < NB; ++j) pb[j] = *(const bf16x8*)&pBsrc[j * 8];

    const int T = K >> 6;
    for (int kt = 0; kt < T; ++kt) {
        __syncthreads();
        #pragma unroll
        for (int j = 0; j < 4; ++j) *(bf16x8*)&As[sra * GPAD64 + ssa + j * 8] = pa[j];
        #pragma unroll
        for (int j = 0; j < NB; ++j) *(bf16x8*)&Bs[srb * GPAD64 + ssb + j * 8] = pb[j];
        __syncthreads();

        if (kt + 1 < T) {
            const short* a = pAsrc + (kt + 1) * 64;
            const short* b = pBsrc + (kt + 1) * 64;
            #pragma unroll
            for (int j = 0; j < 4; ++j) pa[j] = *(const bf16x8*)&a[j * 8];
            #pragma unroll
            for (int j = 0; j < NB; ++j) pb[j] = *(const bf16x8*)&b[j * 8];
        }

        #pragma unroll
        for (int ks = 0; ks < 4; ++ks) {
            bf16x8 af[TM], bfv[2];
            #pragma unroll
            for (int t = 0; t < TM; ++t)
                af[t] = *(const bf16x8*)&As[(wm + t * 32 + col) * GPAD64 + ks * 16 + half_id * 8];
            #pragma unroll
            for (int t = 0; t < 2; ++t)
                bfv[t] = *(const bf16x8*)&Bs[(wn + t * 32 + col) * GPAD64 + ks * 16 + half_id * 8];
            #pragma unroll
            for (int tm = 0; tm < TM; ++tm)
                #pragma unroll
                for (int tn = 0; tn < 2; ++tn)
                    acc[tm][tn] = __builtin_amdgcn_mfma_f32_32x32x16_bf16(
                        af[tm], bfv[tn], acc[tm][tn], 0, 0, 0);
        }
    }

    float* Cf = (float*)Cv;
    short* Cb = (short*)Cv;
    #pragma unroll
    for (int tm = 0; tm < TM; ++tm) {
        #pragma unroll
        for (int r = 0; r < 16; ++r) {
            int row = m0 + wm + tm * 32 + (r & 3) + 8 * (r >> 2) + 4 * half_id;
            #pragma unroll
            for (int tn = 0; tn < 2; ++tn) {
                int cn = n0 + wn + tn * 32 + col;
                size_t off = (size_t)row * N + cn;
                float v = acc[tm][tn][r];
                if (EPI != EPI_NONE && EPI != EPI_QKV) v += bias[cn];
                if (EPI == EPI_QKV && cn < 256) v *= SCALE2Q;
                if (EPI == EPI_GELU) v = gelu_exact(v);
                if (EPI == EPI_PROJ) v += add1[off] + add2[off];
                if (EPI == EPI_RES)  v += add1[off];
                if (EPI == EPI_PROJ || EPI == EPI_RES) Cf[off] = v;
                else                                   Cb[off] = f2bf(v);
            }
        }
    }
}

// ---------------------------------------------------------------------------
// One-time V transpose: qkv[b][n][512+head*32+d] -> vT[(bh*32+d)][n].
// ---------------------------------------------------------------------------
#define VTPAD 136

__global__ __launch_bounds__(256) void vtrans_kernel(const short* __restrict__ qkv,
                                                     short* __restrict__ vT) {
    __shared__ short Tl[32 * VTPAD];
    const int tid = threadIdx.x;
    const int bh = blockIdx.x, c = blockIdx.y;
    const int b = bh >> 3, head = bh & 7;
    {
        int r = tid >> 1, hv = tid & 1;
        const short* src = qkv + (size_t)b * Ndim * 768 + (size_t)(c * 128 + r) * 768
                           + 512 + head * 32 + hv * 16;
        bf16x8 v0 = *(const bf16x8*)&src[0];
        bf16x8 v1 = *(const bf16x8*)&src[8];
        #pragma unroll
        for (int i = 0; i < 8; ++i) {
            Tl[(hv * 16 + i) * VTPAD + r]     = v0[i];
            Tl[(hv * 16 + 8 + i) * VTPAD + r] = v1[i];
        }
    }
    __syncthreads();
    {
        int d = tid >> 3, j16 = (tid & 7) * 16;
        short* dst = vT + (size_t)(bh * 32 + d) * Ndim + c * 128 + j16;
        *(bf16x8*)&dst[0] = *(const bf16x8*)&Tl[d * VTPAD + j16];
        *(bf16x8*)&dst[8] = *(const bf16x8*)&Tl[d * VTPAD + j16 + 8];
    }
}

// ---------------------------------------------------------------------------
// MFMA attention, j-split flash (maxless -> partials additive). Partials bf16.
// Ps single-buffered (wave-private, DS ops in-order -> dbuf was dead weight);
// LDS 29.2 KB -> 5 blocks/CU. exp via raw v_exp_f32.
// ---------------------------------------------------------------------------
#define KVPAD 40
#define CHUNK 128

__global__ __launch_bounds__(256) void attn_mfma_kernel(const short* __restrict__ qkv,
                                                        const short* __restrict__ vT,
                                                        short* __restrict__ opart,
                                                        float* __restrict__ lpart) {
    __shared__ short Ks[CHUNK * KVPAD];
    __shared__ short Vt[32 * VTPAD];
    __shared__ short Ps[4][32 * KVPAD];

    const int tid = threadIdx.x;
    const int w = tid >> 6;
    const int lane = tid & 63;
    const int col = lane & 31;
    const int half_id = lane >> 5;

    const int bh = blockIdx.y;
    const int b = bh >> 3, head = bh & 7;
    const int q0w = blockIdx.x * 128 + w * 32;
    const int part = blockIdx.z;

    const size_t qkvb = (size_t)b * Ndim * 768;
    short* op = opart + (size_t)part * Tdim * 256;
    float* lp = lpart + (size_t)part * Tdim * 8;

    bf16x8 qf[2];
    {
        const short* qrow = qkv + qkvb + (size_t)(q0w + col) * 768 + head * 32;
        #pragma unroll
        for (int kh = 0; kh < 2; ++kh)
            qf[kh] = *(const bf16x8*)&qrow[kh * 16 + half_id * 8];
    }

    bf16x8 vone;
    #pragma unroll
    for (int i = 0; i < 8; ++i) vone[i] = (short)0x3F80;   // bf16 1.0

    f32x16 o_acc = 0.0f, l_acc = 0.0f;

    const int c0 = part * 4;
    for (int c = c0; c < c0 + 4; ++c) {
        if (c != c0) __syncthreads();
        {
            int r = tid >> 1, hv = tid & 1;
            const short* src = qkv + qkvb + (size_t)(c * CHUNK + r) * 768
                               + head * 32 + hv * 16;
            *(bf16x8*)&Ks[r * KVPAD + hv * 16]     = *(const bf16x8*)&src[256];
            *(bf16x8*)&Ks[r * KVPAD + hv * 16 + 8] = *(const bf16x8*)&src[256 + 8];
            int d = tid >> 3, j16 = (tid & 7) * 16;
            const short* vsrc = vT + (size_t)(bh * 32 + d) * Ndim + c * CHUNK + j16;
            *(bf16x8*)&Vt[d * VTPAD + j16]     = *(const bf16x8*)&vsrc[0];
            *(bf16x8*)&Vt[d * VTPAD + j16 + 8] = *(const bf16x8*)&vsrc[8];
        }
        __syncthreads();

        #pragma unroll
        for (int jt = 0; jt < 4; ++jt) {
            short* ps = &Ps[w][0];
            bf16x8 kf0 = *(bf16x8*)&Ks[(jt * 32 + col) * KVPAD + half_id * 8];
            bf16x8 kf1 = *(bf16x8*)&Ks[(jt * 32 + col) * KVPAD + 16 + half_id * 8];
            bf16x8 vf0 = *(bf16x8*)&Vt[col * VTPAD + jt * 32 + half_id * 8];
            bf16x8 vf1 = *(bf16x8*)&Vt[col * VTPAD + jt * 32 + 16 + half_id * 8];

            f32x16 s_acc = 0.0f;
            s_acc = __builtin_amdgcn_mfma_f32_32x32x16_bf16(kf0, qf[0], s_acc, 0, 0, 0);
            s_acc = __builtin_amdgcn_mfma_f32_32x32x16_bf16(kf1, qf[1], s_acc, 0, 0, 0);

            #pragma unroll
            for (int g = 0; g < 4; ++g) {
                float e0 = fexp2(s_acc[g * 4 + 0]);
                float e1 = fexp2(s_acc[g * 4 + 1]);
                float e2 = fexp2(s_acc[g * 4 + 2]);
                float e3 = fexp2(s_acc[g * 4 + 3]);
                uint2 pk;
                pk.x = pack2bf(e0, e1);
                pk.y = pack2bf(e2, e3);
                *(uint2*)&ps[col * KVPAD + g * 8 + half_id * 4] = pk;
            }

            bf16x8 pf0 = *(bf16x8*)&ps[col * KVPAD + half_id * 8];
            bf16x8 pf1 = *(bf16x8*)&ps[col * KVPAD + 16 + half_id * 8];
            o_acc = __builtin_amdgcn_mfma_f32_32x32x16_bf16(pf0, vf0, o_acc, 0, 0, 0);
            o_acc = __builtin_amdgcn_mfma_f32_32x32x16_bf16(pf1, vf1, o_acc, 0, 0, 0);
            l_acc = __builtin_amdgcn_mfma_f32_32x32x16_bf16(pf0, vone, l_acc, 0, 0, 0);
            l_acc = __builtin_amdgcn_mfma_f32_32x32x16_bf16(pf1, vone, l_acc, 0, 0, 0);
        }
    }

    #pragma unroll
    for (int r = 0; r < 16; ++r) {
        int q_r = (r & 3) + 8 * (r >> 2) + 4 * half_id;
        size_t gq = (size_t)(b * Ndim + q0w + q_r);
        op[gq * INdim + head * 32 + col] = f2bf(o_acc[r]);
    }
    if (col < 16) {
        int r = col;
        int q_r = (r & 3) + 8 * (r >> 2) + 4 * half_id;
        lp[(size_t)(b * Ndim + q0w + q_r) * 8 + head] = l_acc[r];
    }
}

// ---------------------------------------------------------------------------
// Combine j-partitions: oat = (O0+O1) / (l0+l1), bf16 in/out, 8 elems/thread.
// ---------------------------------------------------------------------------
__global__ __launch_bounds__(256) void combine_kernel(const short* __restrict__ opart,
                                                      const float* __restrict__ lpart,
                                                      short* __restrict__ oat) {
    int i = blockIdx.x * 256 + threadIdx.x;
    size_t base = (size_t)i * 8;
    int gq = (int)(base >> 8);
    int head = ((int)(base & 255)) >> 5;
    bf16x8 a = ((const bf16x8*)opart)[i];
    bf16x8 b = ((const bf16x8*)(opart + (size_t)Tdim * 256))[i];
    float l = lpart[(size_t)gq * 8 + head] + lpart[(size_t)Tdim * 8 + (size_t)gq * 8 + head];
    float rl = 1.0f / l;
    bf16x8 r;
    #pragma unroll
    for (int j = 0; j < 8; ++j) r[j] = f2bf((bf2f(a[j]) + bf2f(b[j])) * rl);
    ((bf16x8*)oat)[i] = r;
}

// ---------------------------------------------------------------------------
// launch
// ---------------------------------------------------------------------------
extern "C" void kernel_launch(void* const* d_in, const int* in_sizes, int n_in,
                              void* d_out, int out_size, void* d_ws, size_t ws_size,
                              hipStream_t stream) {
    const float* x     = (const float*)d_in[0];
    const float* g1    = (const float*)d_in[2];
    const float* b1    = (const float*)d_in[3];
    const float* Wqkv  = (const float*)d_in[4];
    const float* Wproj = (const float*)d_in[5];
    const float* bproj = (const float*)d_in[6];
    const float* g2    = (const float*)d_in[7];
    const float* b2    = (const float*)d_in[8];
    const float* W1    = (const float*)d_in[9];
    const float* bb1   = (const float*)d_in[10];
    const float* W2    = (const float*)d_in[11];
    const float* bb2   = (const float*)d_in[12];
    float* out = (float*)d_out;

    // workspace:
    //  [0,16M)  h fp32
    //  [16,24M) h_bf
    //  [24,48M) qkv_bf (dead after attn) -> xnew fp32 [24,40M), oat_bf [40,48M)
    //  [48,64M) opart bf16 x2 (dead after combine) -> mid_bf [48,80M)
    //  [80,81M) lpart fp32 [2][Tdim*8]
    //  [81,89M) vT bf16
    //  [89,91M) weights bf16
    char* ws = (char*)d_ws;
    float* h      = (float*)(ws);
    short* h_bf   = (short*)(ws + (size_t)(16u << 20));
    short* qkv_bf = (short*)(ws + (size_t)(24u << 20));
    float* xnew   = (float*)(ws + (size_t)(24u << 20));
    short* oat_bf = (short*)(ws + (size_t)(40u << 20));
    short* opart  = (short*)(ws + (size_t)(48u << 20));
    short* mid_bf = (short*)(ws + (size_t)(48u << 20));
    float* lpart  = (float*)(ws + (size_t)(80u << 20));
    short* vT     = (short*)(ws + (size_t)(81u << 20));
    short* wqkv_b = (short*)(ws + (size_t)(89u << 20));
    short* wproj_b= (short*)(ws + (size_t)(89u << 20) + 768 * 1024);
    short* w1_b   = (short*)(ws + (size_t)(90u << 20));
    short* w2_b   = (short*)(ws + (size_t)(90u << 20) + 512 * 1024);

    // 0) all weights -> bf16 (single dispatch)
    cvt_all_kernel<<<(N4_QKV + N4_PROJ + N4_W1 + N4_W2 + 255) / 256, 256, 0, stream>>>(
        Wqkv, Wproj, W1, W2, wqkv_b, wproj_b, w1_b, w2_b);

    // 1) LN1: x -> h (fp32) + h_bf
    ln4_kernel<<<Tdim / 4, 256, 0, stream>>>(x, g1, b1, h, h_bf);
    // 2) qkv_bf = h_bf @ Wqkv^T, q columns pre-scaled by 32^-0.5*log2e
    gemm_mfma<EPI_QKV, 128><<<dim3(768 / 128, Tdim / 128), 256, 0, stream>>>(
        h_bf, wqkv_b, qkv_bf, Tdim, 768, 256, nullptr, nullptr, nullptr);
    // 2b) V transpose (once)
    vtrans_kernel<<<dim3(Bdim * Hdim, Ndim / 128), 256, 0, stream>>>(qkv_bf, vT);
    // 3) attention partials (j-split x2)
    attn_mfma_kernel<<<dim3(Ndim / 128, Bdim * Hdim, 2), 256, 0, stream>>>(
        qkv_bf, vT, opart, lpart);
    // 3b) combine -> oat_bf
    combine_kernel<<<(Tdim * INdim / 8) / 256, 256, 0, stream>>>(opart, lpart, oat_bf);
    // 4) xnew = oat @ Wproj^T + bproj + h + x
    gemm_mfma<EPI_PROJ, 64><<<dim3(256 / 64, Tdim / 128), 256, 0, stream>>>(
        oat_bf, wproj_b, xnew, Tdim, 256, 256, bproj, h, x);
    // 5) LN2: xnew -> h_bf
    ln4_kernel<<<Tdim / 4, 256, 0, stream>>>(xnew, g2, b2, nullptr, h_bf);
    // 6) mid_bf = gelu(h2 @ W1^T + bb1)
    gemm_mfma<EPI_GELU, 128><<<dim3(1024 / 128, Tdim / 128), 256, 0, stream>>>(
        h_bf, w1_b, mid_bf, Tdim, 1024, 256, bb1, nullptr, nullptr);
    // 7) out = xnew + mid @ W2^T + bb2
    gemm_mfma<EPI_RES, 64><<<dim3(256 / 64, Tdim / 128), 256, 0, stream>>>(
        mid_bf, w2_b, out, Tdim, 256, 1024, bb2, xnew, nullptr);
}